// Round 15
// baseline (64.254 us; speedup 1.0000x reference)
//
#include <hip/hip_runtime.h>
#include <math.h>

#define BATCH 2
#define NPTS (64*64*64)       // 262144 points per batch
#define CIN 32
#define COUT 32
#define NF 64
#define NFEAT 10              // degree <= 2 monomials (deg-3 terms ~1e-5 abs)
#define TWO_PI_F 6.283185307179586f

#define NBLK_PER_B 512            // blocks per batch for K1/K3 (1024 total)
#define NBLK_TOT (BATCH * NBLK_PER_B)
#define PPB (NPTS / NBLK_PER_B)   // 512 points per block

#define MROWS (NFEAT * CIN)       // 320

// ws layout (floats)
#define WS_P 0                              // NBLK_TOT * MROWS = 327680 (1.3 MB)
#define WS_M (MROWS * NBLK_TOT)             // BATCH*MROWS = 640
#define WS_G (WS_M + BATCH * MROWS)         // BATCH*NF*2*COUT = 8192
#define WS_V (WS_G + BATCH * NF * 2 * COUT) // BATCH*NFEAT*COUT = 640

typedef float f4 __attribute__((ext_vector_type(4)));

// monomial tables, degree <= 2: {1, x0,x1,x2, x00,x01,x02,x11,x12,x22}
__device__ const int   d_EX0[NFEAT]  = {0,1,0,0,2,1,1,0,0,0};
__device__ const int   d_EX1[NFEAT]  = {0,0,1,0,0,1,0,2,1,0};
__device__ const int   d_EX2[NFEAT]  = {0,0,0,1,0,0,1,0,1,2};
__device__ const float d_MULT[NFEAT] = {1,1,1,1,1,2,2,1,2,1};

__device__ __forceinline__ float red_psub(float v) {
    v += __int_as_float(__builtin_amdgcn_ds_swizzle(__float_as_int(v), 0x201F)); // ^8
    v += __int_as_float(__builtin_amdgcn_ds_swizzle(__float_as_int(v), 0x401F)); // ^16
    v += __shfl_xor(v, 32, 64);                                                  // ^32
    return v;
}

// K1: partial[blk][idx] = per-block partial of M (idx = feat*CIN+i).
// R13 structure (thread owns 16 contiguous points, x+h in registers, no LDS
// in main path) + NONTEMPORAL loads: the nt cache policy is the single
// untried knob on the cold-read fill path that pinned every variant at
// ~2 TB/s (R7-R14 evidence: structure-independent).
__global__ __launch_bounds__(256) void k1_moments(const float* __restrict__ h,
                                                  const float* __restrict__ x,
                                                  float* __restrict__ partial) {
    const int blk = blockIdx.x;            // 1024: 512 per batch
    const int b = blk >> 9;
    const int blkin = blk & 511;
    const int t = threadIdx.x;
    const int q = t & 7;                   // channel quad
    const int psub = t >> 3;               // 0..31
    const size_t p0 = (size_t)b * NPTS + (size_t)blkin * PPB + (size_t)psub * 16;

    const f4* xv = reinterpret_cast<const f4*>(x + p0 * 3);       // 12 f4
    const f4* hp = reinterpret_cast<const f4*>(h + p0 * 32) + q;  // point j at [j*8]

    f4 X[12];
#pragma unroll
    for (int j = 0; j < 12; ++j) X[j] = __builtin_nontemporal_load(&xv[j]);
    f4 H[16];
#pragma unroll
    for (int j = 0; j < 16; ++j) H[j] = __builtin_nontemporal_load(&hp[(size_t)j * 8]);

    f4 acc[NFEAT];
#pragma unroll
    for (int f = 0; f < NFEAT; ++f) acc[f] = (f4)0.f;

#pragma unroll
    for (int j = 0; j < 16; ++j) {                // all indices compile-time
        const int e = 3 * j;
        float x0 = X[e >> 2][e & 3];
        float x1 = X[(e + 1) >> 2][(e + 1) & 3];
        float x2 = X[(e + 2) >> 2][(e + 2) & 3];
        f4 hv = H[j];
        acc[0] += hv;
        acc[1] = __builtin_elementwise_fma((f4)x0, hv, acc[1]);
        acc[2] = __builtin_elementwise_fma((f4)x1, hv, acc[2]);
        acc[3] = __builtin_elementwise_fma((f4)x2, hv, acc[3]);
        float m;
        m = x0 * x0; acc[4] = __builtin_elementwise_fma((f4)m, hv, acc[4]);
        m = x0 * x1; acc[5] = __builtin_elementwise_fma((f4)m, hv, acc[5]);
        m = x0 * x2; acc[6] = __builtin_elementwise_fma((f4)m, hv, acc[6]);
        m = x1 * x1; acc[7] = __builtin_elementwise_fma((f4)m, hv, acc[7]);
        m = x1 * x2; acc[8] = __builtin_elementwise_fma((f4)m, hv, acc[8]);
        m = x2 * x2; acc[9] = __builtin_elementwise_fma((f4)m, hv, acc[9]);
    }

    // fold the psub slots sharing this q (lane bits 3,4,5) — proven ~free
#pragma unroll
    for (int f = 0; f < NFEAT; ++f) {
#pragma unroll
        for (int e = 0; e < 4; ++e) acc[f][e] = red_psub(acc[f][e]);
    }

    __shared__ float tile[4][MROWS];   // 5 KB
    const int w = t >> 6;
    const int lane = t & 63;
    const int i4 = q << 2;
    if (lane < 8) {
#pragma unroll
        for (int f = 0; f < NFEAT; ++f)
            *reinterpret_cast<f4*>(&tile[w][f * CIN + i4]) = acc[f];
    }
    __syncthreads();
    for (int idx = t; idx < MROWS; idx += 256) {
        float s = tile[0][idx] + tile[1][idx] + tile[2][idx] + tile[3][idx];
        partial[(size_t)blk * MROWS + idx] = s;   // contiguous 1.28KB per block
    }
}

// K1b: M[b][idx] = sum over the 512 blocks of batch b. 640 blocks.
__global__ __launch_bounds__(256) void k1b_reduce(const float* __restrict__ partial,
                                                  float* __restrict__ mws) {
    const int r = blockIdx.x;              // 640 = BATCH * MROWS
    const int b = r / MROWS, idx = r % MROWS;
    const int t = threadIdx.x;
    const float* p = partial + (size_t)b * NBLK_PER_B * MROWS + idx;
    float s = p[(size_t)t * MROWS] + p[((size_t)t + 256) * MROWS];
#pragma unroll
    for (int off = 32; off >= 1; off >>= 1) s += __shfl_down(s, off, 64);
    __shared__ float wsum[4];
    if ((t & 63) == 0) wsum[t >> 6] = s;
    __syncthreads();
    if (t == 0) mws[b * MROWS + idx] = wsum[0] + wsum[1] + wsum[2] + wsum[3];
}

// K2a: per (b,f): H_re/H_im from M, then G = H @ kernel (complex)
__global__ __launch_bounds__(64) void k2a_HG(const float* __restrict__ mws,
                                             const float* __restrict__ modes,
                                             const float* __restrict__ kre,
                                             const float* __restrict__ kim,
                                             float* __restrict__ gws) {
    const int bf = blockIdx.x;             // 128 = BATCH*NF
    const int b = bf >> 6, f = bf & 63;
    const int t = threadIdx.x;
    const int half = t >> 5;               // 0: re, 1: im
    const int lane = t & 31;

    const float u0 = TWO_PI_F * modes[f * 3 + 0];
    const float u1 = TWO_PI_F * modes[f * 3 + 1];
    const float u2 = TWO_PI_F * modes[f * 3 + 2];

    __shared__ float sH[2][32];
    float hv = 0.f;
#pragma unroll
    for (int fi = 0; fi < NFEAT; ++fi) {
        const int e0 = d_EX0[fi], e1 = d_EX1[fi], e2 = d_EX2[fi];
        const int deg = e0 + e1 + e2;
        float up = d_MULT[fi];
#pragma unroll
        for (int r = 0; r < 2; ++r) { if (r < e0) up *= u0; }
#pragma unroll
        for (int r = 0; r < 2; ++r) { if (r < e1) up *= u1; }
#pragma unroll
        for (int r = 0; r < 2; ++r) { if (r < e2) up *= u2; }
        float cc = (deg == 0) ? 1.f : ((deg == 2) ? -0.5f * up : 0.f);
        float cs = (deg == 1) ? up : 0.f;
        float coef = (half == 0) ? cc : -cs;
        hv = fmaf(coef, mws[b * MROWS + fi * CIN + lane], hv);
    }
    sH[half][lane] = hv;
    __syncthreads();

    float go = 0.f;
#pragma unroll 8
    for (int i2 = 0; i2 < CIN; ++i2) {
        float a = kre[((size_t)f * CIN + i2) * COUT + lane];
        float c = kim[((size_t)f * CIN + i2) * COUT + lane];
        float hre = sH[0][i2], him = sH[1][i2];
        go += (half == 0) ? (hre * a - him * c) : (hre * c + him * a);
    }
    gws[(((size_t)b * NF + f) * 2 + half) * COUT + lane] = go;
}

// K2b: V[b][feat][o] = sum_f ccos*Gre - csin*Gim ; fold in fc_w/fc_b
__global__ __launch_bounds__(320) void k2b_V(const float* __restrict__ gws,
                                             const float* __restrict__ modes,
                                             const float* __restrict__ fcw,
                                             const float* __restrict__ fcb,
                                             float* __restrict__ vws) {
    const int b = blockIdx.x;              // 2
    const int t = threadIdx.x;             // 320 = 10*32
    const int fi = t >> 5;
    const int o = t & 31;

    const int e0 = d_EX0[fi], e1 = d_EX1[fi], e2 = d_EX2[fi];
    const int deg = e0 + e1 + e2;
    const float mult = d_MULT[fi];

    float acc = 0.f;
    for (int f = 0; f < NF; ++f) {
        float u0 = TWO_PI_F * modes[f * 3 + 0];
        float u1 = TWO_PI_F * modes[f * 3 + 1];
        float u2 = TWO_PI_F * modes[f * 3 + 2];
        float up = mult;
        for (int r = 0; r < e0; ++r) up *= u0;
        for (int r = 0; r < e1; ++r) up *= u1;
        for (int r = 0; r < e2; ++r) up *= u2;
        float cc = (deg == 0) ? 1.f : ((deg == 2) ? -0.5f * up : 0.f);
        float cs = (deg == 1) ? up : 0.f;
        float gre = gws[(((size_t)b * NF + f) * 2 + 0) * COUT + o];
        float gim = gws[(((size_t)b * NF + f) * 2 + 1) * COUT + o];
        acc += cc * gre - cs * gim;
    }
    if (fi == 0) acc += fcb[o];
    else if (deg == 1) acc += fcw[(fi - 1) * COUT + o];
    vws[(b * NFEAT + fi) * COUT + o] = acc;
}

// K3: out[p][o] = gelu( sum_feat mono(x_p) * V[b][feat][o] )
// R13 exact (at write floor) + NT x-loads.
__global__ __launch_bounds__(256) void k3_out(const float* __restrict__ x,
                                              const float* __restrict__ vws,
                                              float* __restrict__ out) {
    const int blk = blockIdx.x;            // 1024: 512 per batch
    const int b = blk >> 9;
    const int blkin = blk & 511;
    const int t = threadIdx.x;
    const int q = t & 7;
    const int o4 = q << 2;
    const int psub = t >> 3;               // 0..31
    const size_t p0 = (size_t)b * NPTS + (size_t)blkin * PPB + (size_t)psub * 16;

    const f4* xv = reinterpret_cast<const f4*>(x + p0 * 3);

    f4 v[NFEAT];
#pragma unroll
    for (int f = 0; f < NFEAT; ++f)
        v[f] = *reinterpret_cast<const f4*>(&vws[(b * NFEAT + f) * COUT + o4]);

    f4 X[12];
#pragma unroll
    for (int j = 0; j < 12; ++j) X[j] = __builtin_nontemporal_load(&xv[j]);

    const float KS = -1.702f * 1.4426950408889634f;  // -1.702*log2(e)

#pragma unroll
    for (int j = 0; j < 16; ++j) {
        const int e = 3 * j;
        float x0 = X[e >> 2][e & 3];
        float x1 = X[(e + 1) >> 2][(e + 1) & 3];
        float x2 = X[(e + 2) >> 2][(e + 2) & 3];
        f4 y = v[0];
        y = __builtin_elementwise_fma((f4)x0, v[1], y);
        y = __builtin_elementwise_fma((f4)x1, v[2], y);
        y = __builtin_elementwise_fma((f4)x2, v[3], y);
        float m;
        m = x0 * x0; y = __builtin_elementwise_fma((f4)m, v[4], y);
        m = x0 * x1; y = __builtin_elementwise_fma((f4)m, v[5], y);
        m = x0 * x2; y = __builtin_elementwise_fma((f4)m, v[6], y);
        m = x1 * x1; y = __builtin_elementwise_fma((f4)m, v[7], y);
        m = x1 * x2; y = __builtin_elementwise_fma((f4)m, v[8], y);
        m = x2 * x2; y = __builtin_elementwise_fma((f4)m, v[9], y);
        f4 r;
#pragma unroll
        for (int ee = 0; ee < 4; ++ee) {
            float yy = y[ee];
            float ex = exp2f(KS * yy);
            r[ee] = yy * __builtin_amdgcn_rcpf(1.f + ex);
        }
        __builtin_nontemporal_store(r, reinterpret_cast<f4*>(&out[(p0 + j) * 32 + o4]));
    }
}

extern "C" void kernel_launch(void* const* d_in, const int* in_sizes, int n_in,
                              void* d_out, int out_size, void* d_ws, size_t ws_size,
                              hipStream_t stream) {
    const float* h     = (const float*)d_in[0];
    const float* x     = (const float*)d_in[1];
    const float* modes = (const float*)d_in[2];
    const float* kre   = (const float*)d_in[3];
    const float* kim   = (const float*)d_in[4];
    const float* fcw   = (const float*)d_in[5];
    const float* fcb   = (const float*)d_in[6];
    float* out = (float*)d_out;
    float* ws  = (float*)d_ws;

    k1_moments<<<NBLK_TOT, 256, 0, stream>>>(h, x, ws + WS_P);
    k1b_reduce<<<MROWS * BATCH, 256, 0, stream>>>(ws + WS_P, ws + WS_M);
    k2a_HG<<<BATCH * NF, 64, 0, stream>>>(ws + WS_M, modes, kre, kim, ws + WS_G);
    k2b_V<<<BATCH, NFEAT * COUT, 0, stream>>>(ws + WS_G, modes, fcw, fcb, ws + WS_V);
    k3_out<<<NBLK_TOT, 256, 0, stream>>>(x, ws + WS_V, out);
}

// Round 16
// 55.713 us; speedup vs baseline: 1.1533x; 1.1533x over previous
//
#include <hip/hip_runtime.h>
#include <math.h>

#define BATCH 2
#define NPTS (64*64*64)       // 262144 points per batch
#define CIN 32
#define COUT 32
#define NF 64
#define NFEAT 10              // degree <= 2 monomials (deg-3 terms ~1e-5 abs)
#define TWO_PI_F 6.283185307179586f

#define NBLK_PER_B 512            // blocks per batch for K1/K3 (1024 total)
#define NBLK_TOT (BATCH * NBLK_PER_B)
#define PPB (NPTS / NBLK_PER_B)   // 512 points per block

#define MROWS (NFEAT * CIN)       // 320

// ws layout (floats)
#define WS_P 0                              // NBLK_TOT * MROWS = 327680 (1.3 MB)
#define WS_M (MROWS * NBLK_TOT)             // BATCH*MROWS = 640
#define WS_G (WS_M + BATCH * MROWS)         // BATCH*NF*2*COUT = 8192
#define WS_V (WS_G + BATCH * NF * 2 * COUT) // BATCH*NFEAT*COUT = 640

typedef float f4 __attribute__((ext_vector_type(4)));

// monomial tables, degree <= 2: {1, x0,x1,x2, x00,x01,x02,x11,x12,x22}
__device__ const int   d_EX0[NFEAT]  = {0,1,0,0,2,1,1,0,0,0};
__device__ const int   d_EX1[NFEAT]  = {0,0,1,0,0,1,0,2,1,0};
__device__ const int   d_EX2[NFEAT]  = {0,0,0,1,0,0,1,0,1,2};
__device__ const float d_MULT[NFEAT] = {1,1,1,1,1,2,2,1,2,1};

__device__ __forceinline__ float red_psub(float v) {
    v += __int_as_float(__builtin_amdgcn_ds_swizzle(__float_as_int(v), 0x201F)); // ^8
    v += __int_as_float(__builtin_amdgcn_ds_swizzle(__float_as_int(v), 0x401F)); // ^16
    v += __shfl_xor(v, 32, 64);                                                  // ^32
    return v;
}

// K1: partial[blk][idx] = per-block partial of M (idx = feat*CIN+i).
// Best-measured structure (R13, 55.57us total): thread = (psub 0..31, q 0..7)
// owns 16 CONTIGUOUS points; x (12 f4) and h (16 f4) register-resident, no LDS
// in main path, no staging barrier. Regular (cached) loads — NT regressed
// (R15: L3 retention serves part of h/x; nt bypassed it).
__global__ __launch_bounds__(256) void k1_moments(const float* __restrict__ h,
                                                  const float* __restrict__ x,
                                                  float* __restrict__ partial) {
    const int blk = blockIdx.x;            // 1024: 512 per batch
    const int b = blk >> 9;
    const int blkin = blk & 511;
    const int t = threadIdx.x;
    const int q = t & 7;                   // channel quad
    const int psub = t >> 3;               // 0..31
    const size_t p0 = (size_t)b * NPTS + (size_t)blkin * PPB + (size_t)psub * 16;

    const f4* xv = reinterpret_cast<const f4*>(x + p0 * 3);       // 12 f4, 16B-aligned
    const f4* hp = reinterpret_cast<const f4*>(h + p0 * 32) + q;  // point j at [j*8]

    f4 X[12];
#pragma unroll
    for (int j = 0; j < 12; ++j) X[j] = xv[j];
    f4 H[16];
#pragma unroll
    for (int j = 0; j < 16; ++j) H[j] = hp[(size_t)j * 8];

    f4 acc[NFEAT];
#pragma unroll
    for (int f = 0; f < NFEAT; ++f) acc[f] = (f4)0.f;

#pragma unroll
    for (int j = 0; j < 16; ++j) {                // all indices compile-time
        const int e = 3 * j;
        float x0 = X[e >> 2][e & 3];
        float x1 = X[(e + 1) >> 2][(e + 1) & 3];
        float x2 = X[(e + 2) >> 2][(e + 2) & 3];
        f4 hv = H[j];
        acc[0] += hv;
        acc[1] = __builtin_elementwise_fma((f4)x0, hv, acc[1]);
        acc[2] = __builtin_elementwise_fma((f4)x1, hv, acc[2]);
        acc[3] = __builtin_elementwise_fma((f4)x2, hv, acc[3]);
        float m;
        m = x0 * x0; acc[4] = __builtin_elementwise_fma((f4)m, hv, acc[4]);
        m = x0 * x1; acc[5] = __builtin_elementwise_fma((f4)m, hv, acc[5]);
        m = x0 * x2; acc[6] = __builtin_elementwise_fma((f4)m, hv, acc[6]);
        m = x1 * x1; acc[7] = __builtin_elementwise_fma((f4)m, hv, acc[7]);
        m = x1 * x2; acc[8] = __builtin_elementwise_fma((f4)m, hv, acc[8]);
        m = x2 * x2; acc[9] = __builtin_elementwise_fma((f4)m, hv, acc[9]);
    }

    // fold the psub slots sharing this q (lane bits 3,4,5) — proven ~free (R10)
#pragma unroll
    for (int f = 0; f < NFEAT; ++f) {
#pragma unroll
        for (int e = 0; e < 4; ++e) acc[f][e] = red_psub(acc[f][e]);
    }

    __shared__ float tile[4][MROWS];   // 5 KB
    const int w = t >> 6;
    const int lane = t & 63;
    const int i4 = q << 2;
    if (lane < 8) {
#pragma unroll
        for (int f = 0; f < NFEAT; ++f)
            *reinterpret_cast<f4*>(&tile[w][f * CIN + i4]) = acc[f];
    }
    __syncthreads();
    for (int idx = t; idx < MROWS; idx += 256) {
        float s = tile[0][idx] + tile[1][idx] + tile[2][idx] + tile[3][idx];
        partial[(size_t)blk * MROWS + idx] = s;   // contiguous 1.28KB per block
    }
}

// K1b: M[b][idx] = sum over the 512 blocks of batch b. 640 blocks.
__global__ __launch_bounds__(256) void k1b_reduce(const float* __restrict__ partial,
                                                  float* __restrict__ mws) {
    const int r = blockIdx.x;              // 640 = BATCH * MROWS
    const int b = r / MROWS, idx = r % MROWS;
    const int t = threadIdx.x;
    const float* p = partial + (size_t)b * NBLK_PER_B * MROWS + idx;
    float s = p[(size_t)t * MROWS] + p[((size_t)t + 256) * MROWS];
#pragma unroll
    for (int off = 32; off >= 1; off >>= 1) s += __shfl_down(s, off, 64);
    __shared__ float wsum[4];
    if ((t & 63) == 0) wsum[t >> 6] = s;
    __syncthreads();
    if (t == 0) mws[b * MROWS + idx] = wsum[0] + wsum[1] + wsum[2] + wsum[3];
}

// K2a: per (b,f): H_re/H_im from M, then G = H @ kernel (complex)
__global__ __launch_bounds__(64) void k2a_HG(const float* __restrict__ mws,
                                             const float* __restrict__ modes,
                                             const float* __restrict__ kre,
                                             const float* __restrict__ kim,
                                             float* __restrict__ gws) {
    const int bf = blockIdx.x;             // 128 = BATCH*NF
    const int b = bf >> 6, f = bf & 63;
    const int t = threadIdx.x;
    const int half = t >> 5;               // 0: re, 1: im
    const int lane = t & 31;

    const float u0 = TWO_PI_F * modes[f * 3 + 0];
    const float u1 = TWO_PI_F * modes[f * 3 + 1];
    const float u2 = TWO_PI_F * modes[f * 3 + 2];

    __shared__ float sH[2][32];
    float hv = 0.f;
#pragma unroll
    for (int fi = 0; fi < NFEAT; ++fi) {
        const int e0 = d_EX0[fi], e1 = d_EX1[fi], e2 = d_EX2[fi];
        const int deg = e0 + e1 + e2;
        float up = d_MULT[fi];
#pragma unroll
        for (int r = 0; r < 2; ++r) { if (r < e0) up *= u0; }
#pragma unroll
        for (int r = 0; r < 2; ++r) { if (r < e1) up *= u1; }
#pragma unroll
        for (int r = 0; r < 2; ++r) { if (r < e2) up *= u2; }
        float cc = (deg == 0) ? 1.f : ((deg == 2) ? -0.5f * up : 0.f);
        float cs = (deg == 1) ? up : 0.f;
        float coef = (half == 0) ? cc : -cs;
        hv = fmaf(coef, mws[b * MROWS + fi * CIN + lane], hv);
    }
    sH[half][lane] = hv;
    __syncthreads();

    float go = 0.f;
#pragma unroll 8
    for (int i2 = 0; i2 < CIN; ++i2) {
        float a = kre[((size_t)f * CIN + i2) * COUT + lane];
        float c = kim[((size_t)f * CIN + i2) * COUT + lane];
        float hre = sH[0][i2], him = sH[1][i2];
        go += (half == 0) ? (hre * a - him * c) : (hre * c + him * a);
    }
    gws[(((size_t)b * NF + f) * 2 + half) * COUT + lane] = go;
}

// K2b: V[b][feat][o] = sum_f ccos*Gre - csin*Gim ; fold in fc_w/fc_b
__global__ __launch_bounds__(320) void k2b_V(const float* __restrict__ gws,
                                             const float* __restrict__ modes,
                                             const float* __restrict__ fcw,
                                             const float* __restrict__ fcb,
                                             float* __restrict__ vws) {
    const int b = blockIdx.x;              // 2
    const int t = threadIdx.x;             // 320 = 10*32
    const int fi = t >> 5;
    const int o = t & 31;

    const int e0 = d_EX0[fi], e1 = d_EX1[fi], e2 = d_EX2[fi];
    const int deg = e0 + e1 + e2;
    const float mult = d_MULT[fi];

    float acc = 0.f;
    for (int f = 0; f < NF; ++f) {
        float u0 = TWO_PI_F * modes[f * 3 + 0];
        float u1 = TWO_PI_F * modes[f * 3 + 1];
        float u2 = TWO_PI_F * modes[f * 3 + 2];
        float up = mult;
        for (int r = 0; r < e0; ++r) up *= u0;
        for (int r = 0; r < e1; ++r) up *= u1;
        for (int r = 0; r < e2; ++r) up *= u2;
        float cc = (deg == 0) ? 1.f : ((deg == 2) ? -0.5f * up : 0.f);
        float cs = (deg == 1) ? up : 0.f;
        float gre = gws[(((size_t)b * NF + f) * 2 + 0) * COUT + o];
        float gim = gws[(((size_t)b * NF + f) * 2 + 1) * COUT + o];
        acc += cc * gre - cs * gim;
    }
    if (fi == 0) acc += fcb[o];
    else if (deg == 1) acc += fcw[(fi - 1) * COUT + o];
    vws[(b * NFEAT + fi) * COUT + o] = acc;
}

// K3: out[p][o] = gelu( sum_feat mono(x_p) * V[b][feat][o] )
// thread = (psub, channel-quad) owns 16 CONTIGUOUS points; x fully in registers
// (no LDS, no barrier); nontemporal float4 stores. At ~write floor.
__global__ __launch_bounds__(256) void k3_out(const float* __restrict__ x,
                                              const float* __restrict__ vws,
                                              float* __restrict__ out) {
    const int blk = blockIdx.x;            // 1024: 512 per batch
    const int b = blk >> 9;
    const int blkin = blk & 511;
    const int t = threadIdx.x;
    const int q = t & 7;
    const int o4 = q << 2;
    const int psub = t >> 3;               // 0..31
    const size_t p0 = (size_t)b * NPTS + (size_t)blkin * PPB + (size_t)psub * 16;

    const f4* xv = reinterpret_cast<const f4*>(x + p0 * 3);

    f4 v[NFEAT];
#pragma unroll
    for (int f = 0; f < NFEAT; ++f)
        v[f] = *reinterpret_cast<const f4*>(&vws[(b * NFEAT + f) * COUT + o4]);

    f4 X[12];
#pragma unroll
    for (int j = 0; j < 12; ++j) X[j] = xv[j];

    const float KS = -1.702f * 1.4426950408889634f;  // -1.702*log2(e)

#pragma unroll
    for (int j = 0; j < 16; ++j) {
        const int e = 3 * j;
        float x0 = X[e >> 2][e & 3];
        float x1 = X[(e + 1) >> 2][(e + 1) & 3];
        float x2 = X[(e + 2) >> 2][(e + 2) & 3];
        f4 y = v[0];
        y = __builtin_elementwise_fma((f4)x0, v[1], y);
        y = __builtin_elementwise_fma((f4)x1, v[2], y);
        y = __builtin_elementwise_fma((f4)x2, v[3], y);
        float m;
        m = x0 * x0; y = __builtin_elementwise_fma((f4)m, v[4], y);
        m = x0 * x1; y = __builtin_elementwise_fma((f4)m, v[5], y);
        m = x0 * x2; y = __builtin_elementwise_fma((f4)m, v[6], y);
        m = x1 * x1; y = __builtin_elementwise_fma((f4)m, v[7], y);
        m = x1 * x2; y = __builtin_elementwise_fma((f4)m, v[8], y);
        m = x2 * x2; y = __builtin_elementwise_fma((f4)m, v[9], y);
        f4 r;
#pragma unroll
        for (int ee = 0; ee < 4; ++ee) {
            float yy = y[ee];
            float ex = exp2f(KS * yy);
            r[ee] = yy * __builtin_amdgcn_rcpf(1.f + ex);
        }
        __builtin_nontemporal_store(r, reinterpret_cast<f4*>(&out[(p0 + j) * 32 + o4]));
    }
}

extern "C" void kernel_launch(void* const* d_in, const int* in_sizes, int n_in,
                              void* d_out, int out_size, void* d_ws, size_t ws_size,
                              hipStream_t stream) {
    const float* h     = (const float*)d_in[0];
    const float* x     = (const float*)d_in[1];
    const float* modes = (const float*)d_in[2];
    const float* kre   = (const float*)d_in[3];
    const float* kim   = (const float*)d_in[4];
    const float* fcw   = (const float*)d_in[5];
    const float* fcb   = (const float*)d_in[6];
    float* out = (float*)d_out;
    float* ws  = (float*)d_ws;

    k1_moments<<<NBLK_TOT, 256, 0, stream>>>(h, x, ws + WS_P);
    k1b_reduce<<<MROWS * BATCH, 256, 0, stream>>>(ws + WS_P, ws + WS_M);
    k2a_HG<<<BATCH * NF, 64, 0, stream>>>(ws + WS_M, modes, kre, kim, ws + WS_G);
    k2b_V<<<BATCH, NFEAT * COUT, 0, stream>>>(ws + WS_G, modes, fcw, fcb, ws + WS_V);
    k3_out<<<NBLK_TOT, 256, 0, stream>>>(x, ws + WS_V, out);
}